// Round 1
// baseline (103.798 us; speedup 1.0000x reference)
//
#include <hip/hip_runtime.h>
#include <math.h>

#define BB 32
#define NN 1000
#define CC 81
#define MAX_INST 100
#define MIN_CONF 0.7f
#define NMS_THRESH 0.3f
#define MCAP 1024     // per-batch candidate capacity in LDS (>= NN)
#define RCHUNK 192    // suppression-matrix rows per chunk
#define WMAX 16       // 64-bit words per keep row (1024/64)

// glist record (8 floats, fixed slot b*NN+n):
//   [0..3] = {y1,x1,y2,x2} (only written when valid)
//   [4..7] = {score or -1 (invalid sentinel), cls, orig_idx, 0}

// ---------------- Kernel A: one wave (64 lanes) per ROI ----------------
// Argmax over 81 classes via coalesced lane loads + shuffle reduce; lane 0
// decodes/clips the box and writes the record to its FIXED per-ROI slot.
// No global atomics (deterministic slotting; order recovered by sort in B).
// Block 0 also zeroes d_out (harness poisons it).
__global__ __launch_bounds__(256) void roi_kernel(
    const float* __restrict__ rois,      // B,N,4
    const float* __restrict__ probs,     // B,N,C
    const float* __restrict__ deltas,    // B,N,C,4
    const float* __restrict__ std_dev,   // 4
    float* __restrict__ glist,           // B x NN x 8 (fixed slots)
    float* __restrict__ out)             // B,MAX_INST,6 (zeroed here)
{
  if (blockIdx.x == 0) {
    float4* o4 = (float4*)out;
    for (int i = threadIdx.x; i < BB * MAX_INST * 6 / 4; i += 256)
      o4[i] = make_float4(0.f, 0.f, 0.f, 0.f);
  }

  int wg = blockIdx.x * 4 + (threadIdx.x >> 6);
  if (wg >= BB * NN) return;
  int lane = threadIdx.x & 63;

  const float* p = probs + (size_t)wg * CC;
  float v = p[lane];              // lanes 0..63 cover classes 0..63
  int   c = lane;
  if (lane + 64 < CC) {           // lanes 0..16 also cover classes 64..80
    float v2 = p[lane + 64];
    if (v2 > v) { v = v2; c = lane + 64; }   // lower class wins ties
  }
  // first-occurrence argmax: on ties keep smaller class index
  for (int off = 32; off; off >>= 1) {
    float vo = __shfl_down(v, off);
    int   co = __shfl_down(c, off);
    if (vo > v || (vo == v && co < c)) { v = vo; c = co; }
  }

  if (lane == 0) {
    float4* o = (float4*)(glist + (size_t)wg * 8);
    bool valid = (c > 0) && (v >= MIN_CONF);
    if (valid) {
      float4 dd = *(const float4*)(deltas + ((size_t)wg * CC + c) * 4);
      float4 r4 = *(const float4*)(rois + (size_t)wg * 4);
      float dy = dd.x * std_dev[0], dx = dd.y * std_dev[1];
      float dh = dd.z * std_dev[2], dw = dd.w * std_dev[3];
      float h = r4.z - r4.x, w = r4.w - r4.y;
      float cy = r4.x + 0.5f * h + dy * h;
      float cx = r4.y + 0.5f * w + dx * w;
      h *= expf(dh); w *= expf(dw);
      float y1 = cy - 0.5f * h, x1 = cx - 0.5f * w;
      float y2 = y1 + h,        x2 = x1 + w;
      y1 = fminf(fmaxf(y1, 0.f), 1.f); x1 = fminf(fmaxf(x1, 0.f), 1.f);
      y2 = fminf(fmaxf(y2, 0.f), 1.f); x2 = fminf(fmaxf(x2, 0.f), 1.f);
      o[0] = make_float4(y1, x1, y2, x2);
    }
    int b = wg / NN, n = wg - b * NN;
    o[1] = make_float4(valid ? v : -1.0f, (float)c, (float)n, 0.f);
  }
}

// ------------- Kernel B: one 256-thread block per batch — compact+sort+NMS -------------
__global__ __launch_bounds__(256) void nms_kernel(
    const float* __restrict__ glist,
    float* __restrict__ out)         // B,MAX_INST,6
{
  const int b = blockIdx.x, t = threadIdx.x;

  __shared__ int   lcnt;
  __shared__ float cscore[MCAP];   // append-order scores (LDS-atomic compacted)
  __shared__ int   cidx[MCAP];     // append-order original indices
  __shared__ float sy1[MCAP], sx1[MCAP], sy2[MCAP], sx2[MCAP]; // sorted boxes
  __shared__ int   scls[MCAP];     // sorted classes
  __shared__ float sscr[MCAP];     // sorted scores
  __shared__ unsigned long long rows[RCHUNK][WMAX];
  __shared__ unsigned long long keepw[WMAX];

  const float* base = glist + (size_t)b * NN * 8;

  if (t == 0) lcnt = 0;
  __syncthreads();

  // compact valid records into LDS (order nondeterministic; fixed by sort)
  for (int e = t; e < NN; e += 256) {
    const float4 s = ((const float4*)(base + (size_t)e * 8))[1];
    if (s.x >= 0.f) {
      int pos = atomicAdd(&lcnt, 1);   // LDS atomic — fast, block-local
      cscore[pos] = s.x;
      cidx[pos]   = e;                 // original index within batch
    }
  }
  __syncthreads();

  const int M = lcnt;
  const int W = (M + 63) >> 6;

  // rank = stable-argsort position (score desc, orig idx asc); scatter sorted
  for (int e = t; e < M; e += 256) {
    float sc = cscore[e]; int oi = cidx[e];
    int r = 0;
    for (int j = 0; j < M; ++j) {
      float sj = cscore[j]; int ij = cidx[j];
      if (sj > sc || (sj == sc && ij < oi)) ++r;
    }
    const float4 a = ((const float4*)(base + (size_t)oi * 8))[0];
    const float4 s = ((const float4*)(base + (size_t)oi * 8))[1];
    sy1[r] = a.x; sx1[r] = a.y; sy2[r] = a.z; sx2[r] = a.w;
    scls[r] = (int)s.y; sscr[r] = sc;
  }
  if (t < WMAX) {
    unsigned long long kw = 0ULL;
    int nb = M - t * 64;
    if (nb > 0) kw = (nb >= 64) ? ~0ULL : ((1ULL << nb) - 1ULL);
    keepw[t] = kw;
  }
  __syncthreads();

  // chunked suppression matrix (ballot rows) + wave-serial keep propagation
  const int wv = t >> 6, lane = t & 63;
  for (int c0 = 0; c0 < M; c0 += RCHUNK) {
    int R = min(RCHUNK, M - c0);
    for (int task = wv; task < R * W; task += 4) {
      int i = c0 + task / W;
      int w = task % W;
      int j = w * 64 + lane;
      bool cond = false;
      float iy1 = sy1[i], ix1 = sx1[i], iy2 = sy2[i], ix2 = sx2[i];
      int ic = scls[i];
      if (j < M && j > i && scls[j] == ic) {
        float jy1 = sy1[j], jx1 = sx1[j], jy2 = sy2[j], jx2 = sx2[j];
        float ai = (iy2 - iy1) * (ix2 - ix1);
        float aj = (jy2 - jy1) * (jx2 - jx1);
        float iy = fmaxf(fminf(iy2, jy2) - fmaxf(iy1, jy1), 0.f);
        float ix = fmaxf(fminf(ix2, jx2) - fmaxf(ix1, jx1), 0.f);
        float inter = iy * ix;
        float uni = fmaxf(ai + aj - inter, 1e-8f);
        cond = (inter / uni) > NMS_THRESH;
      }
      unsigned long long word = __ballot(cond);
      if (lane == 0) rows[task / W][w] = word;
    }
    __syncthreads();
    if (t < 64) {
      unsigned long long kw = (t < W) ? keepw[t] : 0ULL;
      for (int i = c0; i < c0 + R; ++i) {
        unsigned long long kwi = __shfl((long long)kw, i >> 6); // uniform lane
        if ((kwi >> (i & 63)) & 1ULL) {
          if (t < W) kw &= ~rows[i - c0][t];
        }
      }
      if (t < W) keepw[t] = kw;
    }
    __syncthreads();
  }

  // slot = popcount of kept entries ahead; write kept rows
  for (int r = t; r < M; r += 256) {
    unsigned long long kwme = keepw[r >> 6];
    if ((kwme >> (r & 63)) & 1ULL) {
      int slot = 0;
      for (int w = 0; w < (r >> 6); ++w) slot += __popcll(keepw[w]);
      slot += __popcll(kwme & ((1ULL << (r & 63)) - 1ULL));
      if (slot < MAX_INST) {
        float* o = out + ((size_t)b * MAX_INST + slot) * 6;
        o[0] = sy1[r]; o[1] = sx1[r]; o[2] = sy2[r]; o[3] = sx2[r];
        o[4] = (float)scls[r]; o[5] = sscr[r];
      }
    }
  }
}

extern "C" void kernel_launch(void* const* d_in, const int* in_sizes, int n_in,
                              void* d_out, int out_size, void* d_ws, size_t ws_size,
                              hipStream_t stream) {
  const float* rois    = (const float*)d_in[0];
  const float* probs   = (const float*)d_in[1];
  const float* deltas  = (const float*)d_in[2];
  const float* std_dev = (const float*)d_in[3];
  float* out = (float*)d_out;

  float* glist = (float*)d_ws;   // B x NN x 8 floats = 1.024 MB (fixed slots)

  roi_kernel<<<(BB * NN + 3) / 4, 256, 0, stream>>>(rois, probs, deltas, std_dev,
                                                    glist, out);
  nms_kernel<<<BB, 256, 0, stream>>>(glist, out);
}

// Round 2
// 98.353 us; speedup vs baseline: 1.0554x; 1.0554x over previous
//
#include <hip/hip_runtime.h>
#include <math.h>

#define BB 32
#define NN 1000
#define CC 81
#define MAX_INST 100
#define MIN_CONF 0.7f
#define NMS_THRESH 0.3f
#define MCAP 1024     // per-batch candidate capacity in LDS (>= NN)
#define RCHUNK 192    // suppression-matrix rows per chunk (general path)
#define WMAX 16       // 64-bit words per keep row (1024/64)

// Workspace layout (ws is re-poisoned by harness every iteration; every word we
// read is rewritten every iteration):
//   sval : float [BB*NN]  @ 0x00000   score if valid else -1 (always written)
//   gcls : int   [BB*NN]  @ 0x20000   class id   (written only when valid)
//   gbox : float4[BB*NN]  @ 0x40000   decoded box (written only when valid)

// ---------------- Kernel A: one HALF-WAVE (32 lanes) per ROI ----------------
// Lane l covers classes {l, l+32, l+64(<81)}; 5-step shuffle reduce within the
// 32-lane group (first-occurrence argmax: lower class wins ties). Lanes 0 and
// 32 decode/clip and write the SoA record for their ROI.
__global__ __launch_bounds__(256) void roi_kernel(
    const float* __restrict__ rois,      // B,N,4
    const float* __restrict__ probs,     // B,N,C
    const float* __restrict__ deltas,    // B,N,C,4
    const float* __restrict__ std_dev,   // 4
    float* __restrict__ sval,
    int* __restrict__ gcls,
    float4* __restrict__ gbox)
{
  int wg = blockIdx.x * 8 + (threadIdx.x >> 5);   // ROI index (8 per block)
  if (wg >= BB * NN) return;
  int hl = threadIdx.x & 31;

  const float* p = probs + (size_t)wg * CC;
  float v = p[hl];              // classes 0..31
  int   c = hl;
  float v2 = p[hl + 32];        // classes 32..63
  if (v2 > v) { v = v2; c = hl + 32; }            // strict >: lower class wins ties
  if (hl < CC - 64) {           // classes 64..80 (lanes 0..16)
    float v3 = p[hl + 64];
    if (v3 > v) { v = v3; c = hl + 64; }
  }
  // reduce within the 32-lane half-wave; result lands in lanes 0 and 32
  for (int off = 16; off; off >>= 1) {
    float vo = __shfl_down(v, off);
    int   co = __shfl_down(c, off);
    if (vo > v || (vo == v && co < c)) { v = vo; c = co; }
  }

  if (hl == 0) {
    bool valid = (c > 0) && (v >= MIN_CONF);
    sval[wg] = valid ? v : -1.0f;
    if (valid) {
      float4 dd = *(const float4*)(deltas + ((size_t)wg * CC + c) * 4);
      float4 r4 = *(const float4*)(rois + (size_t)wg * 4);
      float dy = dd.x * std_dev[0], dx = dd.y * std_dev[1];
      float dh = dd.z * std_dev[2], dw = dd.w * std_dev[3];
      float h = r4.z - r4.x, w = r4.w - r4.y;
      float cy = r4.x + 0.5f * h + dy * h;
      float cx = r4.y + 0.5f * w + dx * w;
      h *= expf(dh); w *= expf(dw);
      float y1 = cy - 0.5f * h, x1 = cx - 0.5f * w;
      float y2 = y1 + h,        x2 = x1 + w;
      y1 = fminf(fmaxf(y1, 0.f), 1.f); x1 = fminf(fmaxf(x1, 0.f), 1.f);
      y2 = fminf(fmaxf(y2, 0.f), 1.f); x2 = fminf(fmaxf(x2, 0.f), 1.f);
      gcls[wg] = c;
      gbox[wg] = make_float4(y1, x1, y2, x2);
    }
  }
}

// ------------- Kernel B: one 256-thread block per batch — compact+sort+NMS -------------
__global__ __launch_bounds__(256) void nms_kernel(
    const float* __restrict__ sval,
    const int* __restrict__ gcls,
    const float4* __restrict__ gbox,
    float* __restrict__ out)         // B,MAX_INST,6
{
  const int b = blockIdx.x, t = threadIdx.x;

  __shared__ int   lcnt;
  __shared__ float lscore[MCAP];   // append-order scores (LDS-atomic compacted)
  __shared__ int   lidx[MCAP];     // append-order original indices
  __shared__ float sy1[MCAP], sx1[MCAP], sy2[MCAP], sx2[MCAP]; // sorted boxes
  __shared__ int   scl[MCAP];      // sorted classes
  __shared__ float sscr[MCAP];     // sorted scores
  __shared__ unsigned long long rows[RCHUNK][WMAX];
  __shared__ unsigned long long keepw[WMAX];

  // zero this batch's output slice (harness poisons d_out)
  float4* ob4 = (float4*)(out + (size_t)b * MAX_INST * 6);
  for (int i = t; i < MAX_INST * 6 / 4; i += 256)
    ob4[i] = make_float4(0.f, 0.f, 0.f, 0.f);

  if (t == 0) lcnt = 0;
  __syncthreads();

  // compact valid records into LDS: coalesced float4 scan of the score array
  const float4* sv4 = (const float4*)(sval + (size_t)b * NN);   // 250 quads
  if (t < NN / 4) {
    float4 s4 = sv4[t];
    if (s4.x >= 0.f) { int q = atomicAdd(&lcnt, 1); lscore[q] = s4.x; lidx[q] = 4 * t + 0; }
    if (s4.y >= 0.f) { int q = atomicAdd(&lcnt, 1); lscore[q] = s4.y; lidx[q] = 4 * t + 1; }
    if (s4.z >= 0.f) { int q = atomicAdd(&lcnt, 1); lscore[q] = s4.z; lidx[q] = 4 * t + 2; }
    if (s4.w >= 0.f) { int q = atomicAdd(&lcnt, 1); lscore[q] = s4.w; lidx[q] = 4 * t + 3; }
  }
  __syncthreads();

  const int M = lcnt;
  const size_t boff = (size_t)b * NN;

  // rank = stable-argsort position (score desc, orig idx asc); scatter sorted
  for (int e = t; e < M; e += 256) {
    float sc = lscore[e]; int oi = lidx[e];
    int r = 0;
    for (int j = 0; j < M; ++j) {
      float sj = lscore[j]; int ij = lidx[j];
      if (sj > sc || (sj == sc && ij < oi)) ++r;
    }
    float4 a = gbox[boff + oi];
    sy1[r] = a.x; sx1[r] = a.y; sy2[r] = a.z; sx2[r] = a.w;
    scl[r] = gcls[boff + oi]; sscr[r] = sc;
  }
  __syncthreads();

  if (M <= 64) {
    // -------- fast path: single-wave greedy NMS, no rows matrix --------
    if (t < 64) {
      const int j = t;
      float jy1 = 0.f, jx1 = 0.f, jy2 = 0.f, jx2 = 0.f, aj = 0.f, jscr = 0.f;
      int jc = -1;
      if (j < M) {
        jy1 = sy1[j]; jx1 = sx1[j]; jy2 = sy2[j]; jx2 = sx2[j];
        jc = scl[j]; jscr = sscr[j];
        aj = (jy2 - jy1) * (jx2 - jx1);
      }
      unsigned long long keep = (M >= 64) ? ~0ULL : ((1ULL << M) - 1ULL);
      for (int i = 0; i < M; ++i) {
        if ((keep >> i) & 1ULL) {
          float iy1 = sy1[i], ix1 = sx1[i], iy2 = sy2[i], ix2 = sx2[i]; // LDS broadcast
          int   ic  = scl[i];
          float ai  = (iy2 - iy1) * (ix2 - ix1);
          bool cond = false;
          if (j > i && j < M && jc == ic) {
            float iy = fmaxf(fminf(iy2, jy2) - fmaxf(iy1, jy1), 0.f);
            float ix = fmaxf(fminf(ix2, jx2) - fmaxf(ix1, jx1), 0.f);
            float inter = iy * ix;
            float uni = fmaxf(ai + aj - inter, 1e-8f);
            cond = (inter / uni) > NMS_THRESH;
          }
          keep &= ~__ballot(cond);
        }
      }
      if (j < M && ((keep >> j) & 1ULL)) {
        int slot = __popcll(keep & ((1ULL << j) - 1ULL));
        if (slot < MAX_INST) {
          float* o = out + ((size_t)b * MAX_INST + slot) * 6;
          o[0] = jy1; o[1] = jx1; o[2] = jy2; o[3] = jx2;
          o[4] = (float)jc; o[5] = jscr;
        }
      }
    }
    return;
  }

  // -------- general path: chunked suppression matrix (any M <= MCAP) --------
  const int W = (M + 63) >> 6;
  if (t < WMAX) {
    unsigned long long kw = 0ULL;
    int nb = M - t * 64;
    if (nb > 0) kw = (nb >= 64) ? ~0ULL : ((1ULL << nb) - 1ULL);
    keepw[t] = kw;
  }
  __syncthreads();

  const int wv = t >> 6, lane = t & 63;
  for (int c0 = 0; c0 < M; c0 += RCHUNK) {
    int R = min(RCHUNK, M - c0);
    for (int task = wv; task < R * W; task += 4) {
      int i = c0 + task / W;
      int w = task % W;
      int j = w * 64 + lane;
      bool cond = false;
      float iy1 = sy1[i], ix1 = sx1[i], iy2 = sy2[i], ix2 = sx2[i];
      int ic = scl[i];
      if (j < M && j > i && scl[j] == ic) {
        float jy1 = sy1[j], jx1 = sx1[j], jy2 = sy2[j], jx2 = sx2[j];
        float ai = (iy2 - iy1) * (ix2 - ix1);
        float aj = (jy2 - jy1) * (jx2 - jx1);
        float iy = fmaxf(fminf(iy2, jy2) - fmaxf(iy1, jy1), 0.f);
        float ix = fmaxf(fminf(ix2, jx2) - fmaxf(ix1, jx1), 0.f);
        float inter = iy * ix;
        float uni = fmaxf(ai + aj - inter, 1e-8f);
        cond = (inter / uni) > NMS_THRESH;
      }
      unsigned long long word = __ballot(cond);
      if (lane == 0) rows[task / W][w] = word;
    }
    __syncthreads();
    if (t < 64) {
      unsigned long long kw = (t < W) ? keepw[t] : 0ULL;
      for (int i = c0; i < c0 + R; ++i) {
        unsigned long long kwi = __shfl((long long)kw, i >> 6); // uniform lane
        if ((kwi >> (i & 63)) & 1ULL) {
          if (t < W) kw &= ~rows[i - c0][t];
        }
      }
      if (t < W) keepw[t] = kw;
    }
    __syncthreads();
  }

  for (int r = t; r < M; r += 256) {
    unsigned long long kwme = keepw[r >> 6];
    if ((kwme >> (r & 63)) & 1ULL) {
      int slot = 0;
      for (int w = 0; w < (r >> 6); ++w) slot += __popcll(keepw[w]);
      slot += __popcll(kwme & ((1ULL << (r & 63)) - 1ULL));
      if (slot < MAX_INST) {
        float* o = out + ((size_t)b * MAX_INST + slot) * 6;
        o[0] = sy1[r]; o[1] = sx1[r]; o[2] = sy2[r]; o[3] = sx2[r];
        o[4] = (float)scl[r]; o[5] = sscr[r];
      }
    }
  }
}

extern "C" void kernel_launch(void* const* d_in, const int* in_sizes, int n_in,
                              void* d_out, int out_size, void* d_ws, size_t ws_size,
                              hipStream_t stream) {
  const float* rois    = (const float*)d_in[0];
  const float* probs   = (const float*)d_in[1];
  const float* deltas  = (const float*)d_in[2];
  const float* std_dev = (const float*)d_in[3];
  float* out = (float*)d_out;

  float*  sval = (float*)d_ws;                          // 128 KB
  int*    gcls = (int*)((char*)d_ws + 0x20000);         // 128 KB
  float4* gbox = (float4*)((char*)d_ws + 0x40000);      // 512 KB

  roi_kernel<<<(BB * NN + 7) / 8, 256, 0, stream>>>(rois, probs, deltas, std_dev,
                                                    sval, gcls, gbox);
  nms_kernel<<<BB, 256, 0, stream>>>(sval, gcls, gbox, out);
}